// Round 1
// baseline (457.305 us; speedup 1.0000x reference)
//
#include <hip/hip_runtime.h>
#include <hip/hip_bf16.h>

#define NHEAD 12
#define TSEQ 2048
#define CEMB 768
#define DHEAD 64
#define NBATCH 4

typedef __attribute__((ext_vector_type(8))) short bf16x8;
typedef __attribute__((ext_vector_type(4))) float f32x4;

__device__ __forceinline__ ushort f2bf(float f) {
  union { float f; unsigned u; } v; v.f = f;
  unsigned u = v.u;
  u += 0x7FFFu + ((u >> 16) & 1u);   // RNE to bf16
  return (ushort)(u >> 16);
}

// ---------- fp32 [R][C] -> bf16 [C][R] (weight pre-transpose) ----------
__global__ void transpose_w(const float* __restrict__ src, ushort* __restrict__ dst,
                            int R, int C) {
  __shared__ float tile[32][33];
  int c0 = blockIdx.x * 32, r0 = blockIdx.y * 32;
  int tx = threadIdx.x, ty = threadIdx.y;  // block (32,8)
#pragma unroll
  for (int j = 0; j < 4; ++j)
    tile[ty + j * 8][tx] = src[(size_t)(r0 + ty + j * 8) * C + c0 + tx];
  __syncthreads();
#pragma unroll
  for (int j = 0; j < 4; ++j)
    dst[(size_t)(c0 + ty + j * 8) * R + r0 + tx] = f2bf(tile[tx][ty + j * 8]);
}

// ---------- bf16 v [BH][T][D] -> vT [BH][D][T] ----------
__global__ void transpose_v(const ushort* __restrict__ src, ushort* __restrict__ dst) {
  __shared__ ushort tile[32][33];
  int bh = blockIdx.z;
  int t0 = blockIdx.x * 32, d0 = blockIdx.y * 32;
  int tx = threadIdx.x, ty = threadIdx.y;  // block (32,8)
  const ushort* s = src + (size_t)bh * TSEQ * DHEAD;
  ushort* o = dst + (size_t)bh * TSEQ * DHEAD;
#pragma unroll
  for (int j = 0; j < 4; ++j)
    tile[ty + j * 8][tx] = s[(t0 + ty + j * 8) * DHEAD + d0 + tx];
  __syncthreads();
#pragma unroll
  for (int j = 0; j < 4; ++j)
    o[(size_t)(d0 + ty + j * 8) * TSEQ + t0 + tx] = tile[tx][ty + j * 8];
}

// ---------- bf16 MFMA GEMM: C[M][N] = A(fp32,[M][K]) * BT(bf16,[N][K])^T + bias ----------
// EPI=0: fp32 out [M][N].  EPI=1: scatter qkv -> q/k/v bf16 [B,H,T,D].
template<int EPI>
__global__ __launch_bounds__(256)
void gemm_bf16(const float* __restrict__ A, const ushort* __restrict__ BT,
               const float* __restrict__ bias, float* __restrict__ outF,
               ushort* __restrict__ qd, ushort* __restrict__ kd, ushort* __restrict__ vd,
               int M, int N, int K)
{
  __shared__ ushort As[128][40];   // BK=32 + 8 pad (80B rows: 16B-aligned, balanced banks)
  __shared__ ushort Bs[128][40];
  const int t = threadIdx.x;
  const int lane = t & 63, wv = t >> 6;
  const int cc = lane & 15, gg = lane >> 4;
  const int m0 = blockIdx.y * 128, n0 = blockIdx.x * 128;
  const int wm = (wv >> 1) * 64, wn = (wv & 1) * 64;
  const int srow = t >> 1, scol = (t & 1) * 16;

  f32x4 acc[4][4];
#pragma unroll
  for (int i = 0; i < 4; ++i)
#pragma unroll
    for (int j = 0; j < 4; ++j) acc[i][j] = (f32x4){0.f, 0.f, 0.f, 0.f};

  const float*  ap = A  + (size_t)(m0 + srow) * K + scol;
  const ushort* bp = BT + (size_t)(n0 + srow) * K + scol;

  for (int kt = 0; kt < K; kt += 32) {
    float4 a0 = *(const float4*)(ap + kt);
    float4 a1 = *(const float4*)(ap + kt + 4);
    float4 a2 = *(const float4*)(ap + kt + 8);
    float4 a3 = *(const float4*)(ap + kt + 12);
    bf16x8 b0 = *(const bf16x8*)(bp + kt);
    bf16x8 b1 = *(const bf16x8*)(bp + kt + 8);
    __syncthreads();   // previous iteration's LDS reads done before overwrite
    bf16x8 w0, w1;
    w0[0] = (short)f2bf(a0.x); w0[1] = (short)f2bf(a0.y);
    w0[2] = (short)f2bf(a0.z); w0[3] = (short)f2bf(a0.w);
    w0[4] = (short)f2bf(a1.x); w0[5] = (short)f2bf(a1.y);
    w0[6] = (short)f2bf(a1.z); w0[7] = (short)f2bf(a1.w);
    w1[0] = (short)f2bf(a2.x); w1[1] = (short)f2bf(a2.y);
    w1[2] = (short)f2bf(a2.z); w1[3] = (short)f2bf(a2.w);
    w1[4] = (short)f2bf(a3.x); w1[5] = (short)f2bf(a3.y);
    w1[6] = (short)f2bf(a3.z); w1[7] = (short)f2bf(a3.w);
    *(bf16x8*)&As[srow][scol]     = w0;
    *(bf16x8*)&As[srow][scol + 8] = w1;
    *(bf16x8*)&Bs[srow][scol]     = b0;
    *(bf16x8*)&Bs[srow][scol + 8] = b1;
    __syncthreads();
    bf16x8 fa[4], fb[4];
#pragma unroll
    for (int i = 0; i < 4; ++i) fa[i] = *(const bf16x8*)&As[wm + i * 16 + cc][8 * gg];
#pragma unroll
    for (int j = 0; j < 4; ++j) fb[j] = *(const bf16x8*)&Bs[wn + j * 16 + cc][8 * gg];
#pragma unroll
    for (int i = 0; i < 4; ++i)
#pragma unroll
      for (int j = 0; j < 4; ++j)
        acc[i][j] = __builtin_amdgcn_mfma_f32_16x16x32_bf16(fa[i], fb[j], acc[i][j], 0, 0, 0);
  }

#pragma unroll
  for (int i = 0; i < 4; ++i) {
#pragma unroll
    for (int j = 0; j < 4; ++j) {
      int gm0 = m0 + wm + i * 16 + gg * 4;
      int gn  = n0 + wn + j * 16 + cc;
      float bv = bias[gn];
      if (EPI == 0) {
#pragma unroll
        for (int e = 0; e < 4; ++e)
          outF[(size_t)(gm0 + e) * N + gn] = acc[i][j][e] + bv;
      } else {
        int which = gn / CEMB;
        int r = gn - which * CEMB;
        int hh = r >> 6, dd = r & 63;
        ushort* dst = which == 0 ? qd : (which == 1 ? kd : vd);
#pragma unroll
        for (int e = 0; e < 4; ++e) {
          int gm = gm0 + e;
          int tt = gm & (TSEQ - 1), bb = gm >> 11;
          dst[(size_t)((bb * NHEAD + hh) * TSEQ + tt) * DHEAD + dd] = f2bf(acc[i][j][e] + bv);
        }
      }
    }
  }
}

// ---------- flash attention: q,k [BH][T][D] bf16, vT [BH][D][T] bf16 -> ybuf fp32 [B][T][C] ----------
__global__ __launch_bounds__(256)
void attn_fwd(const ushort* __restrict__ qg, const ushort* __restrict__ kg,
              const ushort* __restrict__ vTg, float* __restrict__ ybuf)
{
  __shared__ ushort Pl[4][16][80];   // per-wave P tile [16 q][64 key], stride 80 (160B rows)
  const int t = threadIdx.x, lane = t & 63, w = t >> 6;
  const int cc = lane & 15, gg = lane >> 4;
  const int qt = blockIdx.x, bh = blockIdx.y;
  const int b = bh / NHEAD, h = bh - b * NHEAD;
  const int qrow0 = qt * 64 + w * 16;

  const ushort* Qp = qg + ((size_t)bh * TSEQ + qrow0) * DHEAD;
  bf16x8 fq0 = *(const bf16x8*)(Qp + cc * DHEAD + 8 * gg);
  bf16x8 fq1 = *(const bf16x8*)(Qp + cc * DHEAD + 32 + 8 * gg);

  f32x4 o[4];
  float mrow[4], lrow[4];
#pragma unroll
  for (int i = 0; i < 4; ++i) { o[i] = (f32x4){0.f,0.f,0.f,0.f}; mrow[i] = -1e30f; lrow[i] = 0.f; }

  for (int kt = 0; kt <= qt; ++kt) {
    const ushort* Kp = kg + ((size_t)bh * TSEQ + kt * 64) * DHEAD;
    f32x4 s[4];
#pragma unroll
    for (int ct = 0; ct < 4; ++ct) s[ct] = (f32x4){0.f,0.f,0.f,0.f};
#pragma unroll
    for (int ct = 0; ct < 4; ++ct) {
      bf16x8 fk0 = *(const bf16x8*)(Kp + (ct * 16 + cc) * DHEAD + 8 * gg);
      bf16x8 fk1 = *(const bf16x8*)(Kp + (ct * 16 + cc) * DHEAD + 32 + 8 * gg);
      s[ct] = __builtin_amdgcn_mfma_f32_16x16x32_bf16(fq0, fk0, s[ct], 0, 0, 0);
      s[ct] = __builtin_amdgcn_mfma_f32_16x16x32_bf16(fq1, fk1, s[ct], 0, 0, 0);
    }
    if (kt == qt) {   // diagonal tile: causal mask (tile-local compare is exact)
#pragma unroll
      for (int ct = 0; ct < 4; ++ct)
#pragma unroll
        for (int e = 0; e < 4; ++e) {
          int key = ct * 16 + cc;
          int row = w * 16 + gg * 4 + e;
          s[ct][e] = (key <= row) ? s[ct][e] * 0.125f : -1e30f;
        }
    } else {
#pragma unroll
      for (int ct = 0; ct < 4; ++ct)
#pragma unroll
        for (int e = 0; e < 4; ++e) s[ct][e] *= 0.125f;
    }
    float mn[4], al[4], ps[4];
#pragma unroll
    for (int e = 0; e < 4; ++e) {
      float ml = fmaxf(fmaxf(s[0][e], s[1][e]), fmaxf(s[2][e], s[3][e]));
#pragma unroll
      for (int off = 1; off < 16; off <<= 1) ml = fmaxf(ml, __shfl_xor(ml, off, 64));
      mn[e] = fmaxf(mrow[e], ml);
      al[e] = __expf(mrow[e] - mn[e]);
      mrow[e] = mn[e];
      ps[e] = 0.f;
    }
#pragma unroll
    for (int ct = 0; ct < 4; ++ct)
#pragma unroll
      for (int e = 0; e < 4; ++e) { float pp = __expf(s[ct][e] - mn[e]); s[ct][e] = pp; ps[e] += pp; }
#pragma unroll
    for (int e = 0; e < 4; ++e) {
#pragma unroll
      for (int off = 1; off < 16; off <<= 1) ps[e] += __shfl_xor(ps[e], off, 64);
      lrow[e] = lrow[e] * al[e] + ps[e];
    }
#pragma unroll
    for (int dt = 0; dt < 4; ++dt)
#pragma unroll
      for (int e = 0; e < 4; ++e) o[dt][e] *= al[e];
    __syncthreads();   // drain this wave's prior LDS reads (implied waitcnt) before overwrite
#pragma unroll
    for (int ct = 0; ct < 4; ++ct)
#pragma unroll
      for (int e = 0; e < 4; ++e) Pl[w][gg * 4 + e][ct * 16 + cc] = f2bf(s[ct][e]);
    __syncthreads();   // writes visible before fragment reads
    const ushort* Vp = vTg + (size_t)bh * TSEQ * DHEAD + kt * 64;
#pragma unroll
    for (int kc = 0; kc < 2; ++kc) {
      bf16x8 pa = *(const bf16x8*)&Pl[w][cc][kc * 32 + 8 * gg];
#pragma unroll
      for (int dt = 0; dt < 4; ++dt) {
        bf16x8 fv = *(const bf16x8*)(Vp + (size_t)(dt * 16 + cc) * TSEQ + kc * 32 + 8 * gg);
        o[dt] = __builtin_amdgcn_mfma_f32_16x16x32_bf16(pa, fv, o[dt], 0, 0, 0);
      }
    }
  }
#pragma unroll
  for (int dt = 0; dt < 4; ++dt)
#pragma unroll
    for (int e = 0; e < 4; ++e) {
      int row = qrow0 + gg * 4 + e;
      int col = h * DHEAD + dt * 16 + cc;
      ybuf[((size_t)b * TSEQ + row) * CEMB + col] = o[dt][e] / lrow[e];
    }
}

extern "C" void kernel_launch(void* const* d_in, const int* in_sizes, int n_in,
                              void* d_out, int out_size, void* d_ws, size_t ws_size,
                              hipStream_t stream)
{
  (void)in_sizes; (void)n_in; (void)out_size; (void)ws_size;
  const float* x  = (const float*)d_in[0];
  const float* Wa = (const float*)d_in[1];
  const float* ba = (const float*)d_in[2];
  const float* Wo = (const float*)d_in[3];
  const float* bo = (const float*)d_in[4];
  float* out = (float*)d_out;

  char* p = (char*)d_ws;
  ushort* WaT  = (ushort*)p; p += (size_t)3 * CEMB * CEMB * 2;              // [2304][768] bf16
  ushort* WoT  = (ushort*)p; p += (size_t)CEMB * CEMB * 2;                  // [768][768] bf16
  ushort* qb   = (ushort*)p; p += (size_t)NBATCH * NHEAD * TSEQ * DHEAD * 2; // [B,H,T,D]
  ushort* kb   = (ushort*)p; p += (size_t)NBATCH * NHEAD * TSEQ * DHEAD * 2;
  ushort* vtmp = (ushort*)p; p += (size_t)NBATCH * NHEAD * TSEQ * DHEAD * 2;
  ushort* vT   = (ushort*)p; p += (size_t)NBATCH * NHEAD * TSEQ * DHEAD * 2; // [B,H,D,T]
  float*  yb   = (float*)p;  p += (size_t)NBATCH * TSEQ * CEMB * 4;          // fp32 [B,T,C]

  dim3 tb(32, 8);
  transpose_w<<<dim3(3 * CEMB / 32, CEMB / 32), tb, 0, stream>>>(Wa, WaT, CEMB, 3 * CEMB);
  transpose_w<<<dim3(CEMB / 32, CEMB / 32), tb, 0, stream>>>(Wo, WoT, CEMB, CEMB);
  gemm_bf16<1><<<dim3(3 * CEMB / 128, NBATCH * TSEQ / 128), 256, 0, stream>>>(
      x, WaT, ba, nullptr, qb, kb, vtmp, NBATCH * TSEQ, 3 * CEMB, CEMB);
  transpose_v<<<dim3(TSEQ / 32, DHEAD / 32, NBATCH * NHEAD), tb, 0, stream>>>(vtmp, vT);
  attn_fwd<<<dim3(TSEQ / 64, NBATCH * NHEAD), 256, 0, stream>>>(qb, kb, vT, yb);
  gemm_bf16<0><<<dim3(CEMB / 128, NBATCH * TSEQ / 128), 256, 0, stream>>>(
      yb, WoT, bo, out, nullptr, nullptr, nullptr, NBATCH * TSEQ, CEMB, CEMB);
}

// Round 2
// 293.002 us; speedup vs baseline: 1.5608x; 1.5608x over previous
//
#include <hip/hip_runtime.h>
#include <hip/hip_bf16.h>

#define NHEAD 12
#define TSEQ 2048
#define CEMB 768
#define DHEAD 64
#define NBATCH 4

typedef __attribute__((ext_vector_type(8))) short bf16x8;
typedef __attribute__((ext_vector_type(4))) float f32x4;

__device__ __forceinline__ ushort f2bf(float f) {
  union { float f; unsigned u; } v; v.f = f;
  unsigned u = v.u;
  u += 0x7FFFu + ((u >> 16) & 1u);   // RNE to bf16
  return (ushort)(u >> 16);
}

// wave-local LDS ordering (P buffer is wave-private; no block barrier needed)
__device__ __forceinline__ void lds_fence() {
  asm volatile("s_waitcnt lgkmcnt(0)" ::: "memory");
  __builtin_amdgcn_sched_barrier(0);   // rule 18: pin ops after the waitcnt
}

// ---------- fp32 [R][C] -> bf16 [C][R] (weight pre-transpose) ----------
__global__ void transpose_w(const float* __restrict__ src, ushort* __restrict__ dst,
                            int R, int C) {
  __shared__ float tile[32][33];
  int c0 = blockIdx.x * 32, r0 = blockIdx.y * 32;
  int tx = threadIdx.x, ty = threadIdx.y;  // block (32,8)
#pragma unroll
  for (int j = 0; j < 4; ++j)
    tile[ty + j * 8][tx] = src[(size_t)(r0 + ty + j * 8) * C + c0 + tx];
  __syncthreads();
#pragma unroll
  for (int j = 0; j < 4; ++j)
    dst[(size_t)(c0 + ty + j * 8) * R + r0 + tx] = f2bf(tile[tx][ty + j * 8]);
}

// ---------- bf16 v [BH][T][D] -> vT [BH][D][T] ----------
__global__ void transpose_v(const ushort* __restrict__ src, ushort* __restrict__ dst) {
  __shared__ ushort tile[32][33];
  int bh = blockIdx.z;
  int t0 = blockIdx.x * 32, d0 = blockIdx.y * 32;
  int tx = threadIdx.x, ty = threadIdx.y;  // block (32,8)
  const ushort* s = src + (size_t)bh * TSEQ * DHEAD;
  ushort* o = dst + (size_t)bh * TSEQ * DHEAD;
#pragma unroll
  for (int j = 0; j < 4; ++j)
    tile[ty + j * 8][tx] = s[(t0 + ty + j * 8) * DHEAD + d0 + tx];
  __syncthreads();
#pragma unroll
  for (int j = 0; j < 4; ++j)
    o[(size_t)(d0 + ty + j * 8) * TSEQ + t0 + tx] = tile[tx][ty + j * 8];
}

// ---------- bf16 MFMA GEMM: C[M][N] = A(fp32,[M][K]) * BT(bf16,[N][K])^T + bias ----------
// EPI=0: fp32 out [M][N].  EPI=1: scatter qkv -> q/k/v bf16 [B,H,T,D], q pre-scaled by 1/8.
template<int EPI>
__global__ __launch_bounds__(256)
void gemm_bf16(const float* __restrict__ A, const ushort* __restrict__ BT,
               const float* __restrict__ bias, float* __restrict__ outF,
               ushort* __restrict__ qd, ushort* __restrict__ kd, ushort* __restrict__ vd,
               int M, int N, int K)
{
  __shared__ ushort As[128][40];   // BK=32 + 8 pad
  __shared__ ushort Bs[128][40];
  const int t = threadIdx.x;
  const int lane = t & 63, wv = t >> 6;
  const int cc = lane & 15, gg = lane >> 4;
  const int m0 = blockIdx.y * 128, n0 = blockIdx.x * 128;
  const int wm = (wv >> 1) * 64, wn = (wv & 1) * 64;
  const int srow = t >> 1, scol = (t & 1) * 16;

  f32x4 acc[4][4];
#pragma unroll
  for (int i = 0; i < 4; ++i)
#pragma unroll
    for (int j = 0; j < 4; ++j) acc[i][j] = (f32x4){0.f, 0.f, 0.f, 0.f};

  const float*  ap = A  + (size_t)(m0 + srow) * K + scol;
  const ushort* bp = BT + (size_t)(n0 + srow) * K + scol;

  for (int kt = 0; kt < K; kt += 32) {
    float4 a0 = *(const float4*)(ap + kt);
    float4 a1 = *(const float4*)(ap + kt + 4);
    float4 a2 = *(const float4*)(ap + kt + 8);
    float4 a3 = *(const float4*)(ap + kt + 12);
    bf16x8 b0 = *(const bf16x8*)(bp + kt);
    bf16x8 b1 = *(const bf16x8*)(bp + kt + 8);
    __syncthreads();   // previous iteration's LDS reads done before overwrite
    bf16x8 w0, w1;
    w0[0] = (short)f2bf(a0.x); w0[1] = (short)f2bf(a0.y);
    w0[2] = (short)f2bf(a0.z); w0[3] = (short)f2bf(a0.w);
    w0[4] = (short)f2bf(a1.x); w0[5] = (short)f2bf(a1.y);
    w0[6] = (short)f2bf(a1.z); w0[7] = (short)f2bf(a1.w);
    w1[0] = (short)f2bf(a2.x); w1[1] = (short)f2bf(a2.y);
    w1[2] = (short)f2bf(a2.z); w1[3] = (short)f2bf(a2.w);
    w1[4] = (short)f2bf(a3.x); w1[5] = (short)f2bf(a3.y);
    w1[6] = (short)f2bf(a3.z); w1[7] = (short)f2bf(a3.w);
    *(bf16x8*)&As[srow][scol]     = w0;
    *(bf16x8*)&As[srow][scol + 8] = w1;
    *(bf16x8*)&Bs[srow][scol]     = b0;
    *(bf16x8*)&Bs[srow][scol + 8] = b1;
    __syncthreads();
    bf16x8 fa[4], fb[4];
#pragma unroll
    for (int i = 0; i < 4; ++i) fa[i] = *(const bf16x8*)&As[wm + i * 16 + cc][8 * gg];
#pragma unroll
    for (int j = 0; j < 4; ++j) fb[j] = *(const bf16x8*)&Bs[wn + j * 16 + cc][8 * gg];
#pragma unroll
    for (int i = 0; i < 4; ++i)
#pragma unroll
      for (int j = 0; j < 4; ++j)
        acc[i][j] = __builtin_amdgcn_mfma_f32_16x16x32_bf16(fa[i], fb[j], acc[i][j], 0, 0, 0);
  }

#pragma unroll
  for (int i = 0; i < 4; ++i) {
#pragma unroll
    for (int j = 0; j < 4; ++j) {
      int gm0 = m0 + wm + i * 16 + gg * 4;
      int gn  = n0 + wn + j * 16 + cc;
      float bv = bias[gn];
      if (EPI == 0) {
#pragma unroll
        for (int e = 0; e < 4; ++e)
          outF[(size_t)(gm0 + e) * N + gn] = acc[i][j][e] + bv;
      } else {
        int which = gn / CEMB;
        int r = gn - which * CEMB;
        int hh = r >> 6, dd = r & 63;
        ushort* dst = which == 0 ? qd : (which == 1 ? kd : vd);
        float sc = (which == 0) ? 0.125f : 1.0f;   // fold 1/sqrt(D) into Q (exact)
#pragma unroll
        for (int e = 0; e < 4; ++e) {
          int gm = gm0 + e;
          int tt = gm & (TSEQ - 1), bb = gm >> 11;
          dst[(size_t)((bb * NHEAD + hh) * TSEQ + tt) * DHEAD + dd] = f2bf((acc[i][j][e] + bv) * sc);
        }
      }
    }
  }
}

// ---------- flash attention: q,k [BH][T][D] bf16, vT [BH][D][T] bf16 -> ybuf fp32 [B][T][C] ----------
// Work-balanced: block bx handles q-tiles bx and NT-1-bx (each block = NT+1 key-tiles total).
// No block barriers: P tile is wave-private, ordered with wave-local lgkmcnt.
__global__ __launch_bounds__(256)
void attn_fwd(const ushort* __restrict__ qg, const ushort* __restrict__ kg,
              const ushort* __restrict__ vTg, float* __restrict__ ybuf)
{
  __shared__ ushort Pl[4][16][80];   // per-wave P tile [16 q][64 key], stride 80
  const int t = threadIdx.x, lane = t & 63, w = t >> 6;
  const int cc = lane & 15, gg = lane >> 4;
  const int NT = TSEQ / 64;
  const int bx = blockIdx.x, bh = blockIdx.y;
  const int b = bh / NHEAD, h = bh - b * NHEAD;

  for (int pass = 0; pass < 2; ++pass) {
    const int qt = pass ? (NT - 1 - bx) : bx;
    const int qrow0 = qt * 64 + w * 16;

    const ushort* Qp = qg + ((size_t)bh * TSEQ + qrow0) * DHEAD;
    bf16x8 fq0 = *(const bf16x8*)(Qp + cc * DHEAD + 8 * gg);
    bf16x8 fq1 = *(const bf16x8*)(Qp + cc * DHEAD + 32 + 8 * gg);

    f32x4 o[4];
    float mrow[4], lrow[4];
#pragma unroll
    for (int i = 0; i < 4; ++i) { o[i] = (f32x4){0.f,0.f,0.f,0.f}; mrow[i] = -1e30f; lrow[i] = 0.f; }

    for (int kt = 0; kt <= qt; ++kt) {
      const ushort* Kp = kg + ((size_t)bh * TSEQ + kt * 64) * DHEAD;
      f32x4 s[4];
#pragma unroll
      for (int ct = 0; ct < 4; ++ct) s[ct] = (f32x4){0.f,0.f,0.f,0.f};
#pragma unroll
      for (int ct = 0; ct < 4; ++ct) {
        bf16x8 fk0 = *(const bf16x8*)(Kp + (ct * 16 + cc) * DHEAD + 8 * gg);
        bf16x8 fk1 = *(const bf16x8*)(Kp + (ct * 16 + cc) * DHEAD + 32 + 8 * gg);
        s[ct] = __builtin_amdgcn_mfma_f32_16x16x32_bf16(fq0, fk0, s[ct], 0, 0, 0);
        s[ct] = __builtin_amdgcn_mfma_f32_16x16x32_bf16(fq1, fk1, s[ct], 0, 0, 0);
      }
      if (kt == qt) {   // diagonal tile: causal mask (Q already pre-scaled by 1/8)
#pragma unroll
        for (int ct = 0; ct < 4; ++ct)
#pragma unroll
          for (int e = 0; e < 4; ++e) {
            int key = ct * 16 + cc;
            int row = w * 16 + gg * 4 + e;
            if (key > row) s[ct][e] = -1e30f;
          }
      }
      float mn[4], al[4], ps[4];
#pragma unroll
      for (int e = 0; e < 4; ++e) {
        float ml = fmaxf(fmaxf(s[0][e], s[1][e]), fmaxf(s[2][e], s[3][e]));
#pragma unroll
        for (int off = 1; off < 16; off <<= 1) ml = fmaxf(ml, __shfl_xor(ml, off, 64));
        mn[e] = fmaxf(mrow[e], ml);
        al[e] = __expf(mrow[e] - mn[e]);
        mrow[e] = mn[e];
        ps[e] = 0.f;
      }
#pragma unroll
      for (int ct = 0; ct < 4; ++ct)
#pragma unroll
        for (int e = 0; e < 4; ++e) { float pp = __expf(s[ct][e] - mn[e]); s[ct][e] = pp; ps[e] += pp; }
#pragma unroll
      for (int e = 0; e < 4; ++e) {
#pragma unroll
        for (int off = 1; off < 16; off <<= 1) ps[e] += __shfl_xor(ps[e], off, 64);
        lrow[e] = lrow[e] * al[e] + ps[e];
      }
#pragma unroll
      for (int dt = 0; dt < 4; ++dt)
#pragma unroll
        for (int e = 0; e < 4; ++e) o[dt][e] *= al[e];
#pragma unroll
      for (int ct = 0; ct < 4; ++ct)
#pragma unroll
        for (int e = 0; e < 4; ++e) Pl[w][gg * 4 + e][ct * 16 + cc] = f2bf(s[ct][e]);
      lds_fence();   // wave-local: P writes complete before fragment reads
      const ushort* Vp = vTg + (size_t)bh * TSEQ * DHEAD + kt * 64;
#pragma unroll
      for (int kc = 0; kc < 2; ++kc) {
        bf16x8 pa = *(const bf16x8*)&Pl[w][cc][kc * 32 + 8 * gg];
#pragma unroll
        for (int dt = 0; dt < 4; ++dt) {
          bf16x8 fv = *(const bf16x8*)(Vp + (size_t)(dt * 16 + cc) * TSEQ + kc * 32 + 8 * gg);
          o[dt] = __builtin_amdgcn_mfma_f32_16x16x32_bf16(pa, fv, o[dt], 0, 0, 0);
        }
      }
    }
#pragma unroll
    for (int dt = 0; dt < 4; ++dt)
#pragma unroll
      for (int e = 0; e < 4; ++e) {
        int row = qrow0 + gg * 4 + e;
        int col = h * DHEAD + dt * 16 + cc;
        ybuf[((size_t)b * TSEQ + row) * CEMB + col] = o[dt][e] / lrow[e];
      }
  }
}

extern "C" void kernel_launch(void* const* d_in, const int* in_sizes, int n_in,
                              void* d_out, int out_size, void* d_ws, size_t ws_size,
                              hipStream_t stream)
{
  (void)in_sizes; (void)n_in; (void)out_size; (void)ws_size;
  const float* x  = (const float*)d_in[0];
  const float* Wa = (const float*)d_in[1];
  const float* ba = (const float*)d_in[2];
  const float* Wo = (const float*)d_in[3];
  const float* bo = (const float*)d_in[4];
  float* out = (float*)d_out;

  char* p = (char*)d_ws;
  ushort* WaT  = (ushort*)p; p += (size_t)3 * CEMB * CEMB * 2;              // [2304][768] bf16
  ushort* WoT  = (ushort*)p; p += (size_t)CEMB * CEMB * 2;                  // [768][768] bf16
  ushort* qb   = (ushort*)p; p += (size_t)NBATCH * NHEAD * TSEQ * DHEAD * 2; // [B,H,T,D]
  ushort* kb   = (ushort*)p; p += (size_t)NBATCH * NHEAD * TSEQ * DHEAD * 2;
  ushort* vtmp = (ushort*)p; p += (size_t)NBATCH * NHEAD * TSEQ * DHEAD * 2;
  ushort* vT   = (ushort*)p; p += (size_t)NBATCH * NHEAD * TSEQ * DHEAD * 2; // [B,H,D,T]
  float*  yb   = (float*)p;  p += (size_t)NBATCH * TSEQ * CEMB * 4;          // fp32 [B,T,C]

  dim3 tb(32, 8);
  transpose_w<<<dim3(3 * CEMB / 32, CEMB / 32), tb, 0, stream>>>(Wa, WaT, CEMB, 3 * CEMB);
  transpose_w<<<dim3(CEMB / 32, CEMB / 32), tb, 0, stream>>>(Wo, WoT, CEMB, CEMB);
  gemm_bf16<1><<<dim3(3 * CEMB / 128, NBATCH * TSEQ / 128), 256, 0, stream>>>(
      x, WaT, ba, nullptr, qb, kb, vtmp, NBATCH * TSEQ, 3 * CEMB, CEMB);
  transpose_v<<<dim3(TSEQ / 32, DHEAD / 32, NBATCH * NHEAD), tb, 0, stream>>>(vtmp, vT);
  attn_fwd<<<dim3(TSEQ / 128, NBATCH * NHEAD), 256, 0, stream>>>(qb, kb, vT, yb);
  gemm_bf16<0><<<dim3(CEMB / 128, NBATCH * TSEQ / 128), 256, 0, stream>>>(
      yb, WoT, bo, out, nullptr, nullptr, nullptr, NBATCH * TSEQ, CEMB, CEMB);
}